// Round 5
// baseline (430.575 us; speedup 1.0000x reference)
//
#include <hip/hip_runtime.h>
#include <hip/hip_cooperative_groups.h>
#include <hip/hip_bf16.h>
#include <math.h>

namespace cg = cooperative_groups;

#define Bn 8
#define Nn 2048
#define Dn 256

typedef short short8 __attribute__((ext_vector_type(8)));
typedef float floatx4 __attribute__((ext_vector_type(4)));

__device__ __forceinline__ short f2bf_bits(float f) {
    __bf16 h = (__bf16)f;
    return __builtin_bit_cast(short, h);
}

__device__ __forceinline__ float bf2f(short s) {
    unsigned u = ((unsigned)(unsigned short)s) << 16;
    return __builtin_bit_cast(float, u);
}

__device__ __forceinline__ void gl_lds16(const void* gsrc, void* ldst) {
    __builtin_amdgcn_global_load_lds(
        (const __attribute__((address_space(1))) void*)gsrc,
        (__attribute__((address_space(3))) void*)ldst, 16, 0, 0);
}

__device__ __forceinline__ float sigmoidf_(float z) {
    return 1.0f / (1.0f + __expf(-z));
}

// ---- fused cooperative kernel: 256 blocks x 512 threads (1 block/CU) -------
// P0 transpose -> P1 projxn -> P2 sim x4 -> P3 deg -> P4 colsum -> P5 final
// grid.sync() between phases (device-scope fence included).

__global__ __launch_bounds__(512) void k_fused(
    const float* __restrict__ x, const float* __restrict__ W_fp,
    short* __restrict__ Wt,
    const float* __restrict__ b_fp, const float* __restrict__ w_s,
    const float* __restrict__ b_s,
    short* __restrict__ xn, float* __restrict__ sdot, float* __restrict__ nrm,
    float* __restrict__ xpart,
    float* __restrict__ adj, float* __restrict__ degp,
    float* __restrict__ invdeg, float* __restrict__ gpart,
    const float* __restrict__ W_rp, const float* __restrict__ b_rp,
    const float* __restrict__ W_gp, const float* __restrict__ b_gp,
    const float* __restrict__ gamma, const float* __restrict__ beta,
    float* __restrict__ out) {
    cg::grid_group grid = cg::this_grid();
    __shared__ __align__(16) char SM[51200];
    const int t = threadIdx.x;
    const int bid = blockIdx.x;
    const int lane = t & 63, wv = t >> 6;
    const int l15 = lane & 15, q = lane >> 4;

    // =============== P0: Wt[e][d] = bf16(W_fp[d][e]), blocks 0..15 =========
    if (bid < 16) {
        float (*Ts)[65] = (float(*)[65])SM;    // 16640 B
        const int dt0 = (bid >> 2) * 64, et0 = (bid & 3) * 64;
        if (t < 256) {
            const int ro = t >> 4, co = (t & 15) * 4;
            #pragma unroll
            for (int rr = 0; rr < 4; ++rr) {
                int row = rr * 16 + ro;
                float4 v = *(const float4*)(W_fp + (size_t)(dt0 + row) * Dn + et0 + co);
                Ts[row][co + 0] = v.x; Ts[row][co + 1] = v.y;
                Ts[row][co + 2] = v.z; Ts[row][co + 3] = v.w;
            }
        }
        __syncthreads();
        if (t < 256) {
            const int e = t >> 2, cd0 = (t & 3) * 16;
            short8 a, b;
            #pragma unroll
            for (int i = 0; i < 8; ++i) {
                a[i] = f2bf_bits(Ts[cd0 + i][e]);
                b[i] = f2bf_bits(Ts[cd0 + 8 + i][e]);
            }
            *(short8*)(Wt + (size_t)(et0 + e) * Dn + dt0 + cd0) = a;
            *(short8*)(Wt + (size_t)(et0 + e) * Dn + dt0 + cd0 + 8) = b;
        }
    }
    grid.sync();

    // =============== P1: projxn (64 rows/block, all 256 blocks) ============
    {
        short* As = (short*)SM;                  // 8192 B
        short* Bs = (short*)(SM + 8192);         // 32768 B
        float* xsumS = (float*)(SM + 40960);     // 8192 B [wave][d]
        float* redW = (float*)(SM + 49152);      // 512 B [jh][lr]
        float* redN = (float*)(SM + 49664);      // 512 B
        const int bm = bid * 64;
        const int wm = (wv & 3) * 16;            // wave's 16-row slab
        const int jh = wv >> 2;                  // wave's 128-col half

        for (int i = t; i < 2048; i += 512) xsumS[i] = 0.f;

        floatx4 acc[8];
        #pragma unroll
        for (int j = 0; j < 8; ++j) acc[j] = (floatx4){0.f, 0.f, 0.f, 0.f};

        const int rA = t >> 3, cA = (t & 7) * 8;
        const int rB = t >> 3, cB = (t & 7) * 8;

        for (int k0 = 0; k0 < Dn; k0 += 64) {
            const float* gp = x + (size_t)(bm + rA) * Dn + k0 + cA;
            float4 v0 = *(const float4*)gp;
            float4 v1 = *(const float4*)(gp + 4);
            short8 o0;
            o0[0] = f2bf_bits(v0.x); o0[1] = f2bf_bits(v0.y);
            o0[2] = f2bf_bits(v0.z); o0[3] = f2bf_bits(v0.w);
            o0[4] = f2bf_bits(v1.x); o0[5] = f2bf_bits(v1.y);
            o0[6] = f2bf_bits(v1.z); o0[7] = f2bf_bits(v1.w);
            *(short8*)(As + rA * 64 + cA) = o0;
            #pragma unroll
            for (int cc = 0; cc < 4; ++cc)
                gl_lds16(Wt + (size_t)(cc * 64 + rB) * Dn + k0 + cB,
                         Bs + (cc * 64 + rB) * 64 + cB);
            __syncthreads();
            #pragma unroll
            for (int ks = 0; ks < 2; ++ks) {
                short8 af = *(const short8*)(As + (wm + l15) * 64 + ks * 32 + q * 8);
                #pragma unroll
                for (int jj = 0; jj < 8; ++jj) {
                    short8 bfr = *(const short8*)(Bs + (jh * 128 + jj * 16 + l15) * 64 + ks * 32 + q * 8);
                    acc[jj] = __builtin_amdgcn_mfma_f32_16x16x32_bf16(af, bfr, acc[jj], 0, 0, 0);
                }
            }
            {
                float s = 0.f;
                #pragma unroll
                for (int r = 0; r < 8; ++r)
                    s += bf2f(As[(wv * 8 + r) * 64 + lane]);
                xsumS[wv * 256 + k0 + lane] += s;
            }
            __syncthreads();
        }
        if (t < 256) {
            float xs = 0.f;
            #pragma unroll
            for (int w = 0; w < 8; ++w) xs += xsumS[w * 256 + t];
            xpart[(size_t)bid * Dn + t] = xs;
        }
        float bfv[8], wsv[8];
        #pragma unroll
        for (int jj = 0; jj < 8; ++jj) {
            bfv[jj] = b_fp[jh * 128 + jj * 16 + l15];
            wsv[jj] = w_s[jh * 128 + jj * 16 + l15];
        }
        float vv[4][8];
        #pragma unroll
        for (int reg = 0; reg < 4; ++reg) {
            float pw = 0.f, pn = 0.f;
            #pragma unroll
            for (int jj = 0; jj < 8; ++jj) {
                float v = acc[jj][reg] + bfv[jj];
                vv[reg][jj] = v;
                pw += v * wsv[jj];
                pn += v * v;
            }
            #pragma unroll
            for (int m = 1; m < 16; m <<= 1) {
                pw += __shfl_xor(pw, m);
                pn += __shfl_xor(pn, m);
            }
            if (l15 == 0) {
                redW[jh * 64 + wm + q * 4 + reg] = pw;
                redN[jh * 64 + wm + q * 4 + reg] = pn;
            }
        }
        __syncthreads();
        #pragma unroll
        for (int reg = 0; reg < 4; ++reg) {
            int lr = wm + q * 4 + reg;
            float pw = redW[lr] + redW[64 + lr];
            float pn = redN[lr] + redN[64 + lr];
            float nc = fmaxf(sqrtf(pn), 1e-12f);
            float inv = 1.0f / nc;
            int row = bm + lr;
            size_t rbase = (size_t)row * Dn + jh * 128 + l15;
            #pragma unroll
            for (int jj = 0; jj < 8; ++jj)
                xn[rbase + jj * 16] = f2bf_bits(vv[reg][jj] * inv);
            if (jh == 0 && l15 == 0) {
                sdot[row] = pw;
                nrm[row] = nc;
            }
        }
    }
    grid.sync();

    // =============== P2: sim 128x256 tiles, 4 virtual tiles/block ==========
    {
        short* As = (short*)SM;                  // 16384 B
        short* Bs = (short*)(SM + 16384);        // 32768 B
        float* degS = (float*)(SM + 49152);      // 2048 B [4][128]
        const int b = bid & 7;                   // batch pinned per block
        const int wm = (wv >> 2) * 64;           // {0,64}
        const int wn = (wv & 3) * 64;            // {0,64,128,192}
        const int q4 = lane >> 4;
        const int rr = t >> 3, c8 = (t & 7) * 8;
        const short* xb = xn + (size_t)b * Nn * Dn;
        const float bsv = b_s[0];

        for (int vi = 0; vi < 4; ++vi) {
            const int pos = (bid >> 3) * 4 + vi;     // 0..127
            const int by = pos >> 3, cx = pos & 7;
            const int bm = by * 128;
            const int bn = cx * 256;

            floatx4 acc[4][4];
            #pragma unroll
            for (int i = 0; i < 4; ++i)
                #pragma unroll
                for (int j = 0; j < 4; ++j) acc[i][j] = (floatx4){0.f, 0.f, 0.f, 0.f};

            for (int k0 = 0; k0 < Dn; k0 += 64) {
                #pragma unroll
                for (int cc = 0; cc < 2; ++cc) {
                    int r = cc * 64 + rr;
                    gl_lds16(xb + (size_t)(bm + r) * Dn + k0 + c8, As + r * 64 + c8);
                }
                #pragma unroll
                for (int cc = 0; cc < 4; ++cc) {
                    int r = cc * 64 + rr;
                    gl_lds16(xb + (size_t)(bn + r) * Dn + k0 + c8, Bs + r * 64 + c8);
                }
                __syncthreads();
                #pragma unroll
                for (int ks = 0; ks < 2; ++ks) {
                    short8 af[4], bfr[4];
                    #pragma unroll
                    for (int i = 0; i < 4; ++i)
                        af[i] = *(const short8*)(As + (wm + i * 16 + l15) * 64 + ks * 32 + q4 * 8);
                    #pragma unroll
                    for (int j = 0; j < 4; ++j)
                        bfr[j] = *(const short8*)(Bs + (wn + j * 16 + l15) * 64 + ks * 32 + q4 * 8);
                    // SWAPPED operands: reg spans 4 consecutive cols of one row
                    #pragma unroll
                    for (int i = 0; i < 4; ++i)
                        #pragma unroll
                        for (int j = 0; j < 4; ++j)
                            acc[i][j] = __builtin_amdgcn_mfma_f32_16x16x32_bf16(bfr[j], af[i], acc[i][j], 0, 0, 0);
                }
                __syncthreads();
            }
            float srow[4];
            #pragma unroll
            for (int i = 0; i < 4; ++i)
                srow[i] = sigmoidf_(sdot[b * Nn + bm + wm + i * 16 + l15] + bsv);
            float scol[4][4];
            #pragma unroll
            for (int j = 0; j < 4; ++j)
                #pragma unroll
                for (int reg = 0; reg < 4; ++reg)
                    scol[j][reg] = sigmoidf_(sdot[b * Nn + bn + wn + j * 16 + q4 * 4 + reg] + bsv);
            #pragma unroll
            for (int i = 0; i < 4; ++i) {
                float rs = 0.f;
                size_t rbase = ((size_t)b * Nn + (bm + wm + i * 16 + l15)) * Nn + bn + wn + q4 * 4;
                #pragma unroll
                for (int j = 0; j < 4; ++j) {
                    float4 o;
                    float sc;
                    sc = fminf(fmaxf(0.5f * (srow[i] + scol[j][0]), 1e-6f), 1.0f);
                    o.x = fmaxf(sc * acc[i][j][0], 1e-6f);
                    sc = fminf(fmaxf(0.5f * (srow[i] + scol[j][1]), 1e-6f), 1.0f);
                    o.y = fmaxf(sc * acc[i][j][1], 1e-6f);
                    sc = fminf(fmaxf(0.5f * (srow[i] + scol[j][2]), 1e-6f), 1.0f);
                    o.z = fmaxf(sc * acc[i][j][2], 1e-6f);
                    sc = fminf(fmaxf(0.5f * (srow[i] + scol[j][3]), 1e-6f), 1.0f);
                    o.w = fmaxf(sc * acc[i][j][3], 1e-6f);
                    *(float4*)(adj + rbase + (size_t)j * 16) = o;
                    rs += o.x + o.y + o.z + o.w;
                }
                rs += __shfl_xor(rs, 16);
                rs += __shfl_xor(rs, 32);
                if (q4 == 0) degS[(wv & 3) * 128 + wm + i * 16 + l15] = rs;
            }
            __syncthreads();
            if (t < 128)
                degp[((size_t)(b * 8 + cx)) * Nn + bm + t] =
                    degS[t] + degS[128 + t] + degS[256 + t] + degS[384 + t];
            __syncthreads();
        }
    }
    grid.sync();

    // =============== P3: invdeg, blocks 0..31 ==============================
    if (bid < 32) {
        int idx = bid * 512 + t;
        int b = idx >> 11, r = idx & 2047;
        float s = 0.f;
        #pragma unroll
        for (int cx = 0; cx < 8; ++cx)
            s += degp[((size_t)(b * 8 + cx)) * Nn + r];
        invdeg[b * Nn + r] = 1.0f / fmaxf(s, 1e-6f);
    }
    grid.sync();

    // =============== P4: colsum (64-col stripe/block) + gpre partial =======
    {
        float* invS = (float*)SM;                // 8192 B
        float (*part)[64] = (float(*)[64])(SM + 8192);   // 8192 B
        float* csL = (float*)(SM + 16384);       // 256 B
        float* gHalf = (float*)(SM + 16640);     // 2048 B [2][256]
        const int b = bid & 7, ck = bid >> 3;    // ck 0..31
        #pragma unroll
        for (int rc = 0; rc < 4; ++rc) {
            int row = rc * 512 + t;
            invS[row] = invdeg[b * Nn + row];
        }
        __syncthreads();
        const int lc = (t & 15) * 4;
        const int rg = t >> 4;                   // 0..31
        const int c0 = ck * 64;
        float sx = 0.f, sy = 0.f, sz = 0.f, sw = 0.f;
        for (int r = rg; r < Nn; r += 32) {
            float4 v = *(const float4*)(adj + ((size_t)b * Nn + r) * Nn + c0 + lc);
            float w = invS[r];
            sx += v.x * w; sy += v.y * w; sz += v.z * w; sw += v.w * w;
        }
        part[rg][lc + 0] = sx; part[rg][lc + 1] = sy;
        part[rg][lc + 2] = sz; part[rg][lc + 3] = sw;
        __syncthreads();
        if (t < 64) {
            float s = 0.f;
            #pragma unroll
            for (int g = 0; g < 32; ++g) s += part[g][t];
            csL[t] = s * nrm[b * Nn + c0 + t];   // fold proj = nrm * xn
        }
        __syncthreads();
        {
            int h = t >> 8, d = t & 255;         // 2 halves x 32 m's
            float g = 0.f;
            #pragma unroll 4
            for (int mi = 0; mi < 32; ++mi) {
                int m = h * 32 + mi;
                g += csL[m] * bf2f(xn[((size_t)(b * Nn + c0 + m)) * Dn + d]);
            }
            gHalf[h * 256 + d] = g;
        }
        __syncthreads();
        if (t < Dn)
            gpart[(b * 32 + ck) * Dn + t] = gHalf[t] + gHalf[256 + t];
    }
    grid.sync();

    // =============== P5: reduce -> matvecs -> LayerNorm -> out, blocks 0..7
    if (bid < Bn) {
        const int b = bid;
        float* pS = (float*)SM;                  // [2][256]
        float* xS = (float*)(SM + 2048);         // [2][256]
        float* gp_s = (float*)(SM + 4096);
        float* xm_s = (float*)(SM + 5120);
        float* g1_s = (float*)(SM + 6144);
        float* red = (float*)(SM + 7168);        // 8 floats
        const int d = t & 255, c2 = t >> 8;      // c2 in 0..1
        {
            float gs = 0.f, xs = 0.f;
            #pragma unroll
            for (int k = 0; k < 16; ++k) {
                int ck = c2 * 16 + k;
                gs += gpart[(b * 32 + ck) * Dn + d];
                xs += xpart[(b * 32 + ck) * Dn + d];
            }
            pS[c2 * 256 + d] = gs;
            xS[c2 * 256 + d] = xs;
        }
        __syncthreads();
        if (t < Dn) {
            gp_s[t] = (pS[t] + pS[256 + t]) * (1.0f / Nn);
            xm_s[t] = (xS[t] + xS[256 + t]) * (1.0f / Nn);
        }
        __syncthreads();
        {
            float m1 = 0.f;
            #pragma unroll 4
            for (int i = 0; i < 128; ++i) {
                int dd = c2 * 128 + i;
                m1 += gp_s[dd] * W_rp[dd * Dn + d];
            }
            pS[c2 * 256 + d] = m1;
        }
        __syncthreads();
        if (t < Dn) g1_s[t] = b_rp[t] + pS[t] + pS[256 + t];
        __syncthreads();
        {
            float m2 = 0.f;
            #pragma unroll 4
            for (int i = 0; i < 128; ++i) {
                int ee = c2 * 128 + i;
                m2 += g1_s[ee] * W_gp[ee * Dn + d];
            }
            pS[c2 * 256 + d] = m2;
        }
        __syncthreads();
        float h = 0.f;
        if (t < Dn) {
            h = b_gp[t] + pS[t] + pS[256 + t] + xm_s[t];
            float sum = h;
            #pragma unroll
            for (int m = 1; m < 64; m <<= 1) sum += __shfl_xor(sum, m);
            if ((t & 63) == 0) red[t >> 6] = sum;
        }
        __syncthreads();
        float mu = (red[0] + red[1] + red[2] + red[3]) * (1.0f / Dn);
        if (t < Dn) {
            float dv = h - mu;
            float s2 = dv * dv;
            #pragma unroll
            for (int m = 1; m < 64; m <<= 1) s2 += __shfl_xor(s2, m);
            if ((t & 63) == 0) red[4 + (t >> 6)] = s2;
        }
        __syncthreads();
        if (t < Dn) {
            float dv = h - mu;
            float var = (red[4] + red[5] + red[6] + red[7]) * (1.0f / Dn);
            out[b * Dn + t] = dv * rsqrtf(var + 1e-5f) * gamma[t] + beta[t];
        }
    }
}

// ---- launcher --------------------------------------------------------------

extern "C" void kernel_launch(void* const* d_in, const int* in_sizes, int n_in,
                              void* d_out, int out_size, void* d_ws, size_t ws_size,
                              hipStream_t stream) {
    const float* x     = (const float*)d_in[0];
    const float* W_fp  = (const float*)d_in[1];
    const float* b_fp  = (const float*)d_in[2];
    const float* w_s   = (const float*)d_in[3];
    const float* b_s   = (const float*)d_in[4];
    const float* W_rp  = (const float*)d_in[5];
    const float* b_rp  = (const float*)d_in[6];
    const float* W_gp  = (const float*)d_in[7];
    const float* b_gp  = (const float*)d_in[8];
    const float* gamma = (const float*)d_in[9];
    const float* beta  = (const float*)d_in[10];

    float* out = (float*)d_out;
    float* adj = out + Bn * Dn;   // outputs concatenated: out (B*D) then adj (B*N*N)

    char* ws = (char*)d_ws;
    short* xn     = (short*)(ws);                 // 8 MB
    short* Wt     = (short*)(ws + 8388608);       // 128 KB
    float* sdot   = (float*)(ws + 8519680);       // 64 KB
    float* nrm    = (float*)(ws + 8585216);       // 64 KB
    float* degp   = (float*)(ws + 8650752);       // 512 KB (8 batches x 8 cx x 2048)
    float* invdeg = (float*)(ws + 9175040);       // 64 KB  (8 x 2048)
    float* gpart  = (float*)(ws + 9699328);       // 256 KB
    float* xpart  = (float*)(ws + 9961472);       // 256 KB

    void* args[] = {
        (void*)&x, (void*)&W_fp, (void*)&Wt, (void*)&b_fp, (void*)&w_s,
        (void*)&b_s, (void*)&xn, (void*)&sdot, (void*)&nrm, (void*)&xpart,
        (void*)&adj, (void*)&degp, (void*)&invdeg, (void*)&gpart,
        (void*)&W_rp, (void*)&b_rp, (void*)&W_gp, (void*)&b_gp,
        (void*)&gamma, (void*)&beta, (void*)&out
    };
    hipLaunchCooperativeKernel(k_fused, dim3(256), dim3(512), args, 0, stream);
}

// Round 6
// 237.857 us; speedup vs baseline: 1.8102x; 1.8102x over previous
//
#include <hip/hip_runtime.h>
#include <hip/hip_bf16.h>
#include <math.h>

#define Bn 8
#define Nn 2048
#define Dn 256

typedef short short8 __attribute__((ext_vector_type(8)));
typedef float floatx4 __attribute__((ext_vector_type(4)));

__device__ __forceinline__ short f2bf_bits(float f) {
    __bf16 h = (__bf16)f;
    return __builtin_bit_cast(short, h);
}

__device__ __forceinline__ float bf2f(short s) {
    unsigned u = ((unsigned)(unsigned short)s) << 16;
    return __builtin_bit_cast(float, u);
}

__device__ __forceinline__ void gl_lds16(const void* gsrc, void* ldst) {
    __builtin_amdgcn_global_load_lds(
        (const __attribute__((address_space(1))) void*)gsrc,
        (__attribute__((address_space(3))) void*)ldst, 16, 0, 0);
}

__device__ __forceinline__ float sigmoidf_(float z) {
    return 1.0f / (1.0f + __expf(-z));
}

// LDS tiles are stored XOR-swizzled: physical 16B-chunk = logical_chunk ^ (row&7).
// gl_lds16 writes linearly (lane*16), so the global SOURCE column is pre-swizzled;
// all LDS reads apply the same XOR. Spreads b128 reads over all 8 bank-quads
// (16-way conflict -> 8 lanes/quad = hardware minimum).

// ---- Wt[e][d] = bf16(W_fp[d][e]) — tiled, coalesced both sides -------------

__global__ __launch_bounds__(256) void k_transpose(const float* __restrict__ W,
                                                   short* __restrict__ Wt) {
    __shared__ float Ts[64][65];
    const int t = threadIdx.x;
    const int dt0 = blockIdx.x * 64, et0 = blockIdx.y * 64;
    const int ro = t >> 4, co = (t & 15) * 4;
    #pragma unroll
    for (int rr = 0; rr < 4; ++rr) {
        int row = rr * 16 + ro;
        float4 v = *(const float4*)(W + (size_t)(dt0 + row) * Dn + et0 + co);
        Ts[row][co + 0] = v.x; Ts[row][co + 1] = v.y;
        Ts[row][co + 2] = v.z; Ts[row][co + 3] = v.w;
    }
    __syncthreads();
    const int e = t >> 2, cd0 = (t & 3) * 16;
    short8 a, b;
    #pragma unroll
    for (int i = 0; i < 8; ++i) {
        a[i] = f2bf_bits(Ts[cd0 + i][e]);
        b[i] = f2bf_bits(Ts[cd0 + 8 + i][e]);
    }
    *(short8*)(Wt + (size_t)(et0 + e) * Dn + dt0 + cd0) = a;
    *(short8*)(Wt + (size_t)(et0 + e) * Dn + dt0 + cd0 + 8) = b;
}

// ---- K1: proj rows (64 x 256 per block) via MFMA; fused norm, xn, sdot,
//          x column-sum partials. 512 threads: 8 waves = 4 row-slabs x 2
//          column halves; swizzled LDS tiles. -------------------------------

__global__ __launch_bounds__(512) void k_projxn(
    const float* __restrict__ x, const short* __restrict__ Wt,
    const float* __restrict__ b_fp, const float* __restrict__ w_s,
    short* __restrict__ xn, float* __restrict__ sdot, float* __restrict__ nrm,
    float* __restrict__ xpart) {
    __shared__ __align__(16) short As[64 * 64];    // 8 KB
    __shared__ __align__(16) short Bs[256 * 64];   // 32 KB
    __shared__ float xsumS[8 * 256];               // 8 KB  [wave][d]
    __shared__ float redW[2][64];                  // [jh][local row]
    __shared__ float redN[2][64];
    const int t = threadIdx.x;
    const int bm = blockIdx.x * 64;                // global row base in [0, B*N)
    const int lane = t & 63, wv = t >> 6;
    const int wm = (wv & 3) * 16;                  // wave's 16-row slab
    const int jh = wv >> 2;                        // wave's 128-col half
    const int l15 = lane & 15, q = lane >> 4;
    const int rx = l15 & 7;                        // row&7 for fragment reads

    for (int i = t; i < 2048; i += 512) xsumS[i] = 0.f;

    floatx4 acc[8];
    #pragma unroll
    for (int j = 0; j < 8; ++j) acc[j] = (floatx4){0.f, 0.f, 0.f, 0.f};

    const int rA = t >> 3, cA = (t & 7) * 8;       // A staging map (64x64, 8/thr)
    const int rB = t >> 3;                         // B staging row
    const int swzA = ((t & 7) ^ (rA & 7)) * 8;     // swizzled store chunk (A)
    const int swzBsrc = ((t & 7) ^ (rB & 7)) * 8;  // pre-swizzled source col (B)
    const int cB = (t & 7) * 8;                    // linear LDS dest col (B)

    for (int k0 = 0; k0 < Dn; k0 += 64) {
        // A: 64x64 fp32 -> bf16 (8 floats/thread), swizzled store
        const float* gp = x + (size_t)(bm + rA) * Dn + k0 + cA;
        float4 v0 = *(const float4*)gp;
        float4 v1 = *(const float4*)(gp + 4);
        short8 o0;
        o0[0] = f2bf_bits(v0.x); o0[1] = f2bf_bits(v0.y);
        o0[2] = f2bf_bits(v0.z); o0[3] = f2bf_bits(v0.w);
        o0[4] = f2bf_bits(v1.x); o0[5] = f2bf_bits(v1.y);
        o0[6] = f2bf_bits(v1.z); o0[7] = f2bf_bits(v1.w);
        *(short8*)(As + rA * 64 + swzA) = o0;
        // B: Wt slice 256x64, linear LDS dest + pre-swizzled global source
        #pragma unroll
        for (int cc = 0; cc < 4; ++cc)
            gl_lds16(Wt + (size_t)(cc * 64 + rB) * Dn + k0 + swzBsrc,
                     Bs + (cc * 64 + rB) * 64 + cB);
        __syncthreads();
        #pragma unroll
        for (int ks = 0; ks < 2; ++ks) {
            const int cs = ((ks * 4 + q) ^ rx) * 8;    // swizzled read chunk
            short8 af = *(const short8*)(As + (wm + l15) * 64 + cs);
            #pragma unroll
            for (int jj = 0; jj < 8; ++jj) {
                short8 bfr = *(const short8*)(Bs + (jh * 128 + jj * 16 + l15) * 64 + cs);
                acc[jj] = __builtin_amdgcn_mfma_f32_16x16x32_bf16(af, bfr, acc[jj], 0, 0, 0);
            }
        }
        // fused x column-sum: wave wv sums its 8 rows for column `lane`
        {
            float s = 0.f;
            #pragma unroll
            for (int r = 0; r < 8; ++r) {
                int row = wv * 8 + r;
                int idx = ((lane >> 3) ^ (row & 7)) * 8 + (lane & 7);
                s += bf2f(As[row * 64 + idx]);
            }
            xsumS[wv * 256 + k0 + lane] += s;
        }
        __syncthreads();
    }
    // xpart fold (all waves' partials visible after last sync)
    if (t < 256) {
        float xs = 0.f;
        #pragma unroll
        for (int w = 0; w < 8; ++w) xs += xsumS[w * 256 + t];
        xpart[(size_t)blockIdx.x * Dn + t] = xs;
    }
    // epilogue: wave covers 16 rows x its 128-col half (8 frags)
    float bfv[8], wsv[8];
    #pragma unroll
    for (int jj = 0; jj < 8; ++jj) {
        bfv[jj] = b_fp[jh * 128 + jj * 16 + l15];
        wsv[jj] = w_s[jh * 128 + jj * 16 + l15];
    }
    float vv[4][8];
    #pragma unroll
    for (int reg = 0; reg < 4; ++reg) {
        float pw = 0.f, pn = 0.f;
        #pragma unroll
        for (int jj = 0; jj < 8; ++jj) {
            float v = acc[jj][reg] + bfv[jj];
            vv[reg][jj] = v;
            pw += v * wsv[jj];
            pn += v * v;
        }
        #pragma unroll
        for (int m = 1; m < 16; m <<= 1) {
            pw += __shfl_xor(pw, m);
            pn += __shfl_xor(pn, m);
        }
        if (l15 == 0) {
            redW[jh][wm + q * 4 + reg] = pw;
            redN[jh][wm + q * 4 + reg] = pn;
        }
    }
    __syncthreads();
    #pragma unroll
    for (int reg = 0; reg < 4; ++reg) {
        int lr = wm + q * 4 + reg;
        float pw = redW[0][lr] + redW[1][lr];
        float pn = redN[0][lr] + redN[1][lr];
        float nc = fmaxf(sqrtf(pn), 1e-12f);
        float inv = 1.0f / nc;
        int row = bm + lr;
        size_t rbase = (size_t)row * Dn + jh * 128 + l15;
        #pragma unroll
        for (int jj = 0; jj < 8; ++jj)
            xn[rbase + jj * 16] = f2bf_bits(vv[reg][jj] * inv);
        if (jh == 0 && l15 == 0) {
            sdot[row] = pw;
            nrm[row] = nc;
        }
    }
}

// ---- K2: sim = xn@xn^T with 128x256 tiles (512 thr, 8 waves = 2x4 of 64x64).
//          Swizzled LDS; swapped MFMA operands -> float4 stores. XCD swizzle:
//          lin&7 -> batch, each XCD's xn slice = 1 MB (L2-resident). --------

__global__ __launch_bounds__(512) void k_sim(
    const short* __restrict__ xn, const float* __restrict__ sdot,
    const float* __restrict__ b_s, float* __restrict__ adj,
    float* __restrict__ deg_part) {
    __shared__ __align__(16) short As[128 * 64];   // 16 KB
    __shared__ __align__(16) short Bs[256 * 64];   // 32 KB
    __shared__ float degS[4][128];                 // 2 KB
    const int t = threadIdx.x;
    int lin = (blockIdx.z * 16 + blockIdx.y) * 8 + blockIdx.x;    // 0..1023
    const int b = lin & 7;           // batch == XCD (round-robin heuristic)
    const int pos = lin >> 3;        // 0..127 tile within batch
    const int by = pos >> 3, cx = pos & 7;
    const int bm = by * 128;         // row tile (16 tiles)
    const int bn = cx * 256;         // col tile (8 tiles)
    const int lane = t & 63, wv = t >> 6;
    const int wm = (wv >> 2) * 64;   // {0,64}
    const int wn = (wv & 3) * 64;    // {0,64,128,192}
    const int l15 = lane & 15, q4 = lane >> 4;
    const int rx = l15 & 7;
    const int rr = t >> 3, c8 = (t & 7) * 8;
    const int swzSrc = ((t & 7) ^ (rr & 7)) * 8;   // pre-swizzled source col
    const short* xb = xn + (size_t)b * Nn * Dn;

    floatx4 acc[4][4];
    #pragma unroll
    for (int i = 0; i < 4; ++i)
        #pragma unroll
        for (int j = 0; j < 4; ++j) acc[i][j] = (floatx4){0.f, 0.f, 0.f, 0.f};

    for (int k0 = 0; k0 < Dn; k0 += 64) {
        #pragma unroll
        for (int cc = 0; cc < 2; ++cc) {
            int r = cc * 64 + rr;
            gl_lds16(xb + (size_t)(bm + r) * Dn + k0 + swzSrc, As + r * 64 + c8);
        }
        #pragma unroll
        for (int cc = 0; cc < 4; ++cc) {
            int r = cc * 64 + rr;
            gl_lds16(xb + (size_t)(bn + r) * Dn + k0 + swzSrc, Bs + r * 64 + c8);
        }
        __syncthreads();
        #pragma unroll
        for (int ks = 0; ks < 2; ++ks) {
            const int cs = ((ks * 4 + q4) ^ rx) * 8;
            short8 af[4], bfr[4];
            #pragma unroll
            for (int i = 0; i < 4; ++i)
                af[i] = *(const short8*)(As + (wm + i * 16 + l15) * 64 + cs);
            #pragma unroll
            for (int j = 0; j < 4; ++j)
                bfr[j] = *(const short8*)(Bs + (wn + j * 16 + l15) * 64 + cs);
            // SWAPPED operands: thread (l15,q4) reg holds
            // sim[bm+wm+i*16+l15][bn+wn+j*16+q4*4+reg] -> float4 stores
            #pragma unroll
            for (int i = 0; i < 4; ++i)
                #pragma unroll
                for (int j = 0; j < 4; ++j)
                    acc[i][j] = __builtin_amdgcn_mfma_f32_16x16x32_bf16(bfr[j], af[i], acc[i][j], 0, 0, 0);
        }
        __syncthreads();
    }
    // epilogue
    const float bsv = b_s[0];
    float srow[4];
    #pragma unroll
    for (int i = 0; i < 4; ++i)
        srow[i] = sigmoidf_(sdot[b * Nn + bm + wm + i * 16 + l15] + bsv);
    float scol[4][4];
    #pragma unroll
    for (int j = 0; j < 4; ++j)
        #pragma unroll
        for (int reg = 0; reg < 4; ++reg)
            scol[j][reg] = sigmoidf_(sdot[b * Nn + bn + wn + j * 16 + q4 * 4 + reg] + bsv);
    #pragma unroll
    for (int i = 0; i < 4; ++i) {
        float rs = 0.f;
        size_t rbase = ((size_t)b * Nn + (bm + wm + i * 16 + l15)) * Nn + bn + wn + q4 * 4;
        #pragma unroll
        for (int j = 0; j < 4; ++j) {
            float4 o;
            float sc;
            sc = fminf(fmaxf(0.5f * (srow[i] + scol[j][0]), 1e-6f), 1.0f);
            o.x = fmaxf(sc * acc[i][j][0], 1e-6f);
            sc = fminf(fmaxf(0.5f * (srow[i] + scol[j][1]), 1e-6f), 1.0f);
            o.y = fmaxf(sc * acc[i][j][1], 1e-6f);
            sc = fminf(fmaxf(0.5f * (srow[i] + scol[j][2]), 1e-6f), 1.0f);
            o.z = fmaxf(sc * acc[i][j][2], 1e-6f);
            sc = fminf(fmaxf(0.5f * (srow[i] + scol[j][3]), 1e-6f), 1.0f);
            o.w = fmaxf(sc * acc[i][j][3], 1e-6f);
            *(float4*)(adj + rbase + (size_t)j * 16) = o;
            rs += o.x + o.y + o.z + o.w;
        }
        // reduce across the 4 col-quad groups holding the same row
        rs += __shfl_xor(rs, 16);
        rs += __shfl_xor(rs, 32);
        if (q4 == 0) degS[wv & 3][wm + i * 16 + l15] = rs;
    }
    __syncthreads();
    if (t < 128)
        deg_part[((size_t)(b * 8 + cx)) * Nn + bm + t] =
            degS[0][t] + degS[1][t] + degS[2][t] + degS[3][t];
}

// ---- K2b: invdeg[b][r] = 1 / max(sum_cx deg_part, 1e-6) --------------------

__global__ __launch_bounds__(256) void k_deg(const float* __restrict__ deg_part,
                                             float* __restrict__ invdeg) {
    int b = blockIdx.x, t = blockIdx.y * 256 + threadIdx.x;
    float s = 0.f;
    #pragma unroll
    for (int cx = 0; cx < 8; ++cx)
        s += deg_part[((size_t)(b * 8 + cx)) * Nn + t];
    invdeg[b * Nn + t] = 1.0f / fmaxf(s, 1e-6f);
}

// ---- K3: colsum chunk (64 cols, 1024 threads) + fused gpre partial ---------
// gpart[b][ck][d] = sum_{m in chunk} cs[m]*nrm[m]*xn[m,d]  (proj = nrm*xn)

__global__ __launch_bounds__(1024) void k_colsum(
    const float* __restrict__ adj, const float* __restrict__ invdeg,
    const short* __restrict__ xn, const float* __restrict__ nrm,
    float* __restrict__ gpart) {
    int b = blockIdx.x, ck = blockIdx.y, t = threadIdx.x;
    __shared__ float invS[Nn];          // 8 KB
    __shared__ float part[64][64];      // 16 KB
    __shared__ float csL[64];
    __shared__ float gQ[4][Dn];         // 4 KB
    invS[t] = invdeg[b * Nn + t];
    invS[t + 1024] = invdeg[b * Nn + t + 1024];
    __syncthreads();
    const int lc = (t & 15) * 4;        // col offset within 64
    const int rg = t >> 4;              // 0..63 row-group
    const int c0 = ck * 64;
    float sx = 0.f, sy = 0.f, sz = 0.f, sw = 0.f;
    for (int r = rg; r < Nn; r += 64) {
        float4 v = *(const float4*)(adj + ((size_t)b * Nn + r) * Nn + c0 + lc);
        float w = invS[r];
        sx += v.x * w; sy += v.y * w; sz += v.z * w; sw += v.w * w;
    }
    part[rg][lc + 0] = sx; part[rg][lc + 1] = sy;
    part[rg][lc + 2] = sz; part[rg][lc + 3] = sw;
    __syncthreads();
    if (t < 64) {
        float s = 0.f;
        #pragma unroll
        for (int g = 0; g < 64; ++g) s += part[g][t];
        csL[t] = s * nrm[b * Nn + c0 + t];   // fold proj = nrm * xn
    }
    __syncthreads();
    {
        int h = t >> 8, d = t & 255;    // 4 quarters x 16 m's each
        float g = 0.f;
        #pragma unroll 4
        for (int mi = 0; mi < 16; ++mi) {
            int m = h * 16 + mi;
            g += csL[m] * bf2f(xn[((size_t)(b * Nn + c0 + m)) * Dn + d]);
        }
        gQ[h][d] = g;
    }
    __syncthreads();
    if (t < Dn)
        gpart[(b * 32 + ck) * Dn + t] = gQ[0][t] + gQ[1][t] + gQ[2][t] + gQ[3][t];
}

// ---- K4: reduce partials -> matvecs (4-way d-chunk parallel) -> LN -> out --

__global__ __launch_bounds__(1024) void k_final2(
    const float* __restrict__ gpart, const float* __restrict__ xpart,
    const float* __restrict__ W_rp, const float* __restrict__ b_rp,
    const float* __restrict__ W_gp, const float* __restrict__ b_gp,
    const float* __restrict__ gamma, const float* __restrict__ beta,
    float* __restrict__ out) {
    int b = blockIdx.x, t = threadIdx.x;
    const int d = t & 255, c4 = t >> 8;   // c4 in 0..3
    __shared__ float pS[4][Dn];           // partial buffer (reused)
    __shared__ float xS[4][Dn];
    __shared__ float gp_s[Dn];
    __shared__ float xm_s[Dn];
    __shared__ float g1_s[Dn];
    __shared__ float red[8];
    // fold gpart/xpart: each c4 sums 8 chunks
    {
        float gs = 0.f, xs = 0.f;
        #pragma unroll
        for (int k = 0; k < 8; ++k) {
            int ck = c4 * 8 + k;
            gs += gpart[(b * 32 + ck) * Dn + d];
            xs += xpart[(b * 32 + ck) * Dn + d];
        }
        pS[c4][d] = gs;
        xS[c4][d] = xs;
    }
    __syncthreads();
    if (t < Dn) {
        gp_s[t] = (pS[0][t] + pS[1][t] + pS[2][t] + pS[3][t]) * (1.0f / Nn);
        xm_s[t] = (xS[0][t] + xS[1][t] + xS[2][t] + xS[3][t]) * (1.0f / Nn);
    }
    __syncthreads();
    // matvec1: g1 = W_rp^T gp + b_rp, 4-way over d-chunks
    {
        float m1 = 0.f;
        #pragma unroll 4
        for (int i = 0; i < 64; ++i) {
            int dd = c4 * 64 + i;
            m1 += gp_s[dd] * W_rp[dd * Dn + d];
        }
        pS[c4][d] = m1;
    }
    __syncthreads();
    if (t < Dn) g1_s[t] = b_rp[t] + pS[0][t] + pS[1][t] + pS[2][t] + pS[3][t];
    __syncthreads();
    // matvec2: g2 = W_gp^T g1 + b_gp
    {
        float m2 = 0.f;
        #pragma unroll 4
        for (int i = 0; i < 64; ++i) {
            int ee = c4 * 64 + i;
            m2 += g1_s[ee] * W_gp[ee * Dn + d];
        }
        pS[c4][d] = m2;
    }
    __syncthreads();
    float h = 0.f;
    if (t < Dn) {
        h = b_gp[t] + pS[0][t] + pS[1][t] + pS[2][t] + pS[3][t] + xm_s[t];
        float sum = h;
        #pragma unroll
        for (int m = 1; m < 64; m <<= 1) sum += __shfl_xor(sum, m);
        if ((t & 63) == 0) red[t >> 6] = sum;
    }
    __syncthreads();
    float mu = (red[0] + red[1] + red[2] + red[3]) * (1.0f / Dn);
    if (t < Dn) {
        float dv = h - mu;
        float s2 = dv * dv;
        #pragma unroll
        for (int m = 1; m < 64; m <<= 1) s2 += __shfl_xor(s2, m);
        if ((t & 63) == 0) red[4 + (t >> 6)] = s2;
    }
    __syncthreads();
    if (t < Dn) {
        float dv = h - mu;
        float var = (red[4] + red[5] + red[6] + red[7]) * (1.0f / Dn);
        out[b * Dn + t] = dv * rsqrtf(var + 1e-5f) * gamma[t] + beta[t];
    }
}

// ---- launcher --------------------------------------------------------------

extern "C" void kernel_launch(void* const* d_in, const int* in_sizes, int n_in,
                              void* d_out, int out_size, void* d_ws, size_t ws_size,
                              hipStream_t stream) {
    const float* x     = (const float*)d_in[0];
    const float* W_fp  = (const float*)d_in[1];
    const float* b_fp  = (const float*)d_in[2];
    const float* w_s   = (const float*)d_in[3];
    const float* b_s   = (const float*)d_in[4];
    const float* W_rp  = (const float*)d_in[5];
    const float* b_rp  = (const float*)d_in[6];
    const float* W_gp  = (const float*)d_in[7];
    const float* b_gp  = (const float*)d_in[8];
    const float* gamma = (const float*)d_in[9];
    const float* beta  = (const float*)d_in[10];

    float* out = (float*)d_out;
    float* adj = out + Bn * Dn;   // outputs concatenated: out (B*D) then adj (B*N*N)

    char* ws = (char*)d_ws;
    short* xn     = (short*)(ws);                 // 8 MB
    short* Wt     = (short*)(ws + 8388608);       // 128 KB
    float* sdot   = (float*)(ws + 8519680);       // 64 KB
    float* nrm    = (float*)(ws + 8585216);       // 64 KB
    float* degp   = (float*)(ws + 8650752);       // 512 KB (8 batches x 8 cx x 2048)
    float* invdeg = (float*)(ws + 9175040);       // 64 KB  (8 x 2048)
    float* gpart  = (float*)(ws + 9699328);       // 256 KB
    float* xpart  = (float*)(ws + 9961472);       // 256 KB

    k_transpose<<<dim3(4, 4), 256, 0, stream>>>(W_fp, Wt);
    k_projxn<<<(Bn * Nn) / 64, 512, 0, stream>>>(x, Wt, b_fp, w_s, xn, sdot, nrm, xpart);
    k_sim<<<dim3(8, 16, 8), 512, 0, stream>>>(xn, sdot, b_s, adj, degp);
    k_deg<<<dim3(Bn, 8), 256, 0, stream>>>(degp, invdeg);
    k_colsum<<<dim3(Bn, 32), 1024, 0, stream>>>(adj, invdeg, xn, nrm, gpart);
    k_final2<<<Bn, 1024, 0, stream>>>(gpart, xpart, W_rp, b_rp, W_gp, b_gp, gamma, beta, out);
}